// Round 2
// baseline (7352.757 us; speedup 1.0000x reference)
//
#include <hip/hip_runtime.h>
#include <hip/hip_bf16.h>
#include <type_traits>

typedef short bf16x8 __attribute__((ext_vector_type(8)));
typedef float f32x4  __attribute__((ext_vector_type(4)));

#define B_   64
#define T_   512
#define XD_  256
#define H_   1024
#define KT_  1280   // 256 (x) + 1024 (h)
#define NWG  128

// workspace layout (bytes)
#define OFF_WCAT  0UL
#define SZ_WCAT   (3072UL*KT_*2)            // 7,864,320
#define OFF_XB    (OFF_WCAT + SZ_WCAT)
#define SZ_XB     ((unsigned long)T_*B_*XD_*2)   // 16,777,216
#define OFF_RING  (OFF_XB + SZ_XB)
#define SZ_RING   (16UL*B_*H_*4)            // 4,194,304
#define OFF_HBF32 (OFF_RING + SZ_RING)
#define SZ_HBF32  (2UL*B_*H_*4)
#define OFF_HBF16 (OFF_HBF32 + SZ_HBF32)
#define SZ_HBF16  (2UL*B_*H_*2)
#define OFF_PLAN  (OFF_HBF16 + SZ_HBF16)
#define SZ_PLAN   (4096UL)
#define OFF_CNT   (OFF_PLAN + SZ_PLAN)

__device__ __forceinline__ float sigm_(float x) { return 1.f / (1.f + __expf(-x)); }
__device__ __forceinline__ float tanh_(float x) { return 1.f - 2.f / (__expf(2.f * x) + 1.f); }
__device__ __forceinline__ short bf16_of(float f) {
    __hip_bfloat16 h = __float2bfloat16(f);
    return *reinterpret_cast<short*>(&h);
}

// ---- prep: concat W_ih|W_hh into bf16 Wcat[3072][1280] ----
__global__ void prep_wcat(const float* __restrict__ W_ih, const float* __restrict__ W_hh,
                          short* __restrict__ Wcat) {
    const int j = blockIdx.x;              // 0..3071
    for (int k = threadIdx.x; k < KT_; k += 256) {
        float v = (k < XD_) ? W_ih[j * XD_ + k] : W_hh[j * H_ + (k - XD_)];
        Wcat[(long)j * KT_ + k] = bf16_of(v);
    }
}

// ---- prep: transpose x [B][T][X] f32 -> xb [T][B][X] bf16 ----
__global__ void prep_xb(const float* __restrict__ x, short* __restrict__ xb) {
    const long total = (long)T_ * B_ * XD_;
    for (long i = (long)blockIdx.x * blockDim.x + threadIdx.x; i < total;
         i += (long)gridDim.x * blockDim.x) {
        int t   = (int)(i >> 14);
        int rem = (int)(i & 16383);
        int b   = rem >> 8;
        int k   = rem & 255;
        xb[i] = bf16_of(x[((long)(b * T_ + t)) * XD_ + k]);
    }
}

// ---- prep: packed per-step skip plan: bit0=alpha, bit1=beta, bits2+=lag ----
__global__ void prep_plan(const int* __restrict__ w1, const int* __restrict__ w2,
                          const int* __restrict__ ssp, int* __restrict__ plang) {
    int t = threadIdx.x;
    if (t > T_) return;
    if (t == T_) { plang[t] = (1 << 2); return; }
    int ss = ssp[0];
    int a = w1[t] & 1;
    int uz = 0, slot = 0;
    if (t < ss)            { if (2 * t < ss) uz = 1; else slot = ss - t - 1; }
    else if (t - ss < ss)  { uz = 1; }
    else                   { slot = 2 * ss - 1; }
    int bet = uz ? 0 : (w2[t] & 1);
    plang[t] = a | (bet << 1) | ((slot + 1) << 2);
}

// ---- prep: zero state slot 0 + barrier counter ----
__global__ void prep_zero(float* __restrict__ hbf32, short* __restrict__ hbf16,
                          unsigned* __restrict__ cnt) {
    int i = blockIdx.x * blockDim.x + threadIdx.x;
    if (i < B_ * H_) { hbf32[i] = 0.f; hbf16[i] = 0; }
    if (i == 0) *cnt = 0u;
}

// ---- persistent recurrent kernel: 128 WGs (64 col-blocks x 2 batch-halves) ----
__global__ __launch_bounds__(256, 1) void persist_kernel(
    const short* __restrict__ Wcat, const short* __restrict__ xb,
    const float* __restrict__ b_ih, const float* __restrict__ b_hh,
    float* __restrict__ ring, float* __restrict__ hbf32, short* __restrict__ hbf16,
    const int* __restrict__ plang, unsigned* __restrict__ cnt,
    float* __restrict__ out) {

    __shared__ short Wlds[48 * KT_];            // 122,880 B, XOR-swizzled rows
    __shared__ float red[6 * 3 * 64 * 4];       // 18,432 B cross-wave partials
    __shared__ int   planl[T_ + 1];             // 2,052 B

    const int tid = threadIdx.x;
    const int w   = tid >> 6;
    const int l   = tid & 63;
    const int l15 = l & 15;
    const int lhi = l >> 4;
    const int wg  = blockIdx.x;
    const int c0  = (wg >> 1) << 4;    // 16 output cols per WG
    const int m0  = (wg & 1) << 5;     // 32 batch rows per WG
    const int jj  = c0 + l15;

    // --- one-time: W slice -> LDS (swizzled), plan -> LDS ---
    for (int j = tid; j < 48 * 160; j += 256) {   // 7680 x 16B chunks
        int r    = j / 160;
        int cbyt = (j - r * 160) * 16;
        int g    = r >> 4, i = r & 15;
        bf16x8 v = *(const bf16x8*)(Wcat + (long)(g * H_ + c0 + i) * KT_ + (cbyt >> 1));
        *(bf16x8*)((char*)Wlds + r * 2560 + (cbyt ^ ((r & 7) << 4))) = v;
    }
    for (int j = tid; j <= T_; j += 256) planl[j] = plang[j];

    // invariant epilogue constants
    const float brc = b_ih[jj] + b_hh[jj];
    const float bzc = b_ih[H_ + jj] + b_hh[H_ + jj];
    const float bin = b_ih[2 * H_ + jj];
    const float bhn = b_hh[2 * H_ + jj];
    __syncthreads();

    f32x4 acc[3][2];
    const int sw = (l15 & 7) << 4;

    for (int t = 0; t < T_; ++t) {
        const int cur = t & 1, nxt = cur ^ 1;
        const short* hb = hbf16 + cur * (B_ * H_);

        #pragma unroll
        for (int g = 0; g < 3; ++g)
            #pragma unroll
            for (int rt = 0; rt < 2; ++rt) acc[g][rt] = (f32x4){0.f, 0.f, 0.f, 0.f};

        auto gph = [&](auto ITC, const short* a0, int astride, int k0) {
            constexpr int IT = decltype(ITC)::value;
            const short* a1 = a0 + 16 * astride;
            #pragma unroll
            for (int it = 0; it < IT; ++it) {
                bf16x8 A0 = *(const bf16x8*)(a0 + it * 32);
                bf16x8 A1 = *(const bf16x8*)(a1 + it * 32);
                const int cbs = (((k0 + it * 32 + lhi * 8) * 2) ^ sw);
                bf16x8 B0 = *(const bf16x8*)((const char*)Wlds + (l15)      * 2560 + cbs);
                bf16x8 B1 = *(const bf16x8*)((const char*)Wlds + (16 + l15) * 2560 + cbs);
                bf16x8 B2 = *(const bf16x8*)((const char*)Wlds + (32 + l15) * 2560 + cbs);
                acc[0][0] = __builtin_amdgcn_mfma_f32_16x16x32_bf16(A0, B0, acc[0][0], 0, 0, 0);
                acc[0][1] = __builtin_amdgcn_mfma_f32_16x16x32_bf16(A1, B0, acc[0][1], 0, 0, 0);
                acc[1][0] = __builtin_amdgcn_mfma_f32_16x16x32_bf16(A0, B1, acc[1][0], 0, 0, 0);
                acc[1][1] = __builtin_amdgcn_mfma_f32_16x16x32_bf16(A1, B1, acc[1][1], 0, 0, 0);
                acc[2][0] = __builtin_amdgcn_mfma_f32_16x16x32_bf16(A0, B2, acc[2][0], 0, 0, 0);
                acc[2][1] = __builtin_amdgcn_mfma_f32_16x16x32_bf16(A1, B2, acc[2][1], 0, 0, 0);
            }
        };

        // wave0 = pure x (K 0..256); waves 1-3 split h K (0..352..704..1024)
        if (w == 0) {
            gph(std::integral_constant<int, 8>{},
                xb + (long)t * (B_ * XD_) + (m0 + l15) * XD_ + lhi * 8, XD_, 0);
        } else if (w == 1) {
            gph(std::integral_constant<int, 11>{},
                hb + (m0 + l15) * H_ + 0 + lhi * 8, H_, 256 + 0);
        } else if (w == 2) {
            gph(std::integral_constant<int, 11>{},
                hb + (m0 + l15) * H_ + 352 + lhi * 8, H_, 256 + 352);
        } else {
            gph(std::integral_constant<int, 10>{},
                hb + (m0 + l15) * H_ + 704 + lhi * 8, H_, 256 + 704);
        }

        // write partials for tiles this wave doesn't own (owners: wave0->rt0, wave1->rt1)
        #pragma unroll
        for (int g = 0; g < 3; ++g)
            #pragma unroll
            for (int rt = 0; rt < 2; ++rt)
                if (w != rt) {
                    int s = (w < rt) ? w : w - 1;
                    *(f32x4*)&red[(((g * 2 + rt) * 3 + s) * 64 + l) * 4] = acc[g][rt];
                }
        __syncthreads();

        const int   p   = planl[t + 1];
        const float al  = (float)(p & 1);
        const float bet = (float)((p >> 1) & 1);
        const int   lg  = p >> 2;

        if (w < 2) {
            const int rt = w;
            f32x4 Sr, Sz, Xn, Hn;
            {
                f32x4 v0 = acc[0][rt], v1 = acc[1][rt];
                #pragma unroll
                for (int s = 0; s < 3; ++s) {
                    v0 += *(const f32x4*)&red[(((0 * 2 + rt) * 3 + s) * 64 + l) * 4];
                    v1 += *(const f32x4*)&red[(((1 * 2 + rt) * 3 + s) * 64 + l) * 4];
                }
                Sr = v0; Sz = v1;
                const float* rn = &red[((2 * 2 + rt) * 3 * 64 + l) * 4];
                f32x4 s0 = *(const f32x4*)(rn + 0 * 64 * 4);
                f32x4 s1 = *(const f32x4*)(rn + 1 * 64 * 4);
                f32x4 s2 = *(const f32x4*)(rn + 2 * 64 * 4);
                if (rt == 0) { Xn = acc[2][0]; Hn = s0 + s1 + s2; }     // slots = waves1,2,3 (h)
                else         { Xn = s0;        Hn = acc[2][1] + s1 + s2; } // slot0 = wave0 (x)
            }

            float*       ringw = ring  + (long)(t & 15) * (B_ * H_);
            const float* hbc   = hbf32 + cur * (B_ * H_);
            float*       hbn_  = hbf32 + nxt * (B_ * H_);
            short*       h16n  = hbf16 + nxt * (B_ * H_);

            #pragma unroll
            for (int r = 0; r < 4; ++r) {
                const int  m   = m0 + rt * 16 + lhi * 4 + r;
                const long idx = (long)m * H_ + jj;
                float rg = sigm_(Sr[r] + brc);
                float zg = sigm_(Sz[r] + bzc);
                float ng = tanh_(Xn[r] + bin + rg * (Hn[r] + bhn));
                float hbld = hbc[idx];
                float hn = (1.f - zg) * ng + zg * hbld;
                ringw[idx] = hn;
                float sk = 0.f;
                if (bet != 0.f)
                    sk = (lg == 1) ? hn : ring[(long)((t + 1 - lg) & 15) * (B_ * H_) + idx];
                float hbnv = al * hn + bet * sk;
                hbn_[idx]  = hbnv;
                h16n[idx]  = bf16_of(hbnv);
                if (t == T_ - 1) out[idx] = 2.f * hn;
            }
        }
        __syncthreads();

        // device-scope grid barrier (release h writes, acquire others')
        if (tid == 0) {
            __hip_atomic_fetch_add(cnt, 1u, __ATOMIC_RELEASE, __HIP_MEMORY_SCOPE_AGENT);
            const unsigned target = (unsigned)NWG * (unsigned)(t + 1);
            while (__hip_atomic_load(cnt, __ATOMIC_RELAXED, __HIP_MEMORY_SCOPE_AGENT) < target)
                __builtin_amdgcn_s_sleep(1);
            __threadfence();   // acquire: inv L1/L2 so new h is fetched
        }
        __syncthreads();
    }
}

extern "C" void kernel_launch(void* const* d_in, const int* in_sizes, int n_in,
                              void* d_out, int out_size, void* d_ws, size_t ws_size,
                              hipStream_t stream) {
    const float* x    = (const float*)d_in[0];
    const float* W_ih = (const float*)d_in[1];
    const float* W_hh = (const float*)d_in[2];
    const float* b_ih = (const float*)d_in[3];
    const float* b_hh = (const float*)d_in[4];
    const int*   w1   = (const int*)d_in[5];
    const int*   w2   = (const int*)d_in[6];
    const int*   ssp  = (const int*)d_in[7];
    float* out = (float*)d_out;

    char* ws = (char*)d_ws;
    short*    Wcat  = (short*)(ws + OFF_WCAT);
    short*    xbuf  = (short*)(ws + OFF_XB);
    float*    ring  = (float*)(ws + OFF_RING);
    float*    hbf32 = (float*)(ws + OFF_HBF32);
    short*    hbf16 = (short*)(ws + OFF_HBF16);
    int*      plang = (int*)(ws + OFF_PLAN);
    unsigned* cnt   = (unsigned*)(ws + OFF_CNT);

    prep_wcat<<<3072, 256, 0, stream>>>(W_ih, W_hh, Wcat);
    prep_xb<<<8192, 256, 0, stream>>>(x, xbuf);
    prep_plan<<<1, 1024, 0, stream>>>(w1, w2, ssp, plang);
    prep_zero<<<256, 256, 0, stream>>>(hbf32, hbf16, cnt);

    persist_kernel<<<NWG, 256, 0, stream>>>(Wcat, xbuf, b_ih, b_hh, ring,
                                            hbf32, hbf16, plang, cnt, out);
}

// Round 3
// 2508.365 us; speedup vs baseline: 2.9313x; 2.9313x over previous
//
#include <hip/hip_runtime.h>
#include <hip/hip_bf16.h>
#include <type_traits>

typedef short bf16x8 __attribute__((ext_vector_type(8)));
typedef short bf16x4 __attribute__((ext_vector_type(4)));
typedef float f32x4  __attribute__((ext_vector_type(4)));
typedef unsigned long long u64;

#define B_   64
#define T_   512
#define XD_  256
#define H_   1024
#define NWG  256

// workspace layout (bytes)
#define OFF_WCAT  0UL
#define SZ_WCAT   (3072UL*1280*2)                 // 7,864,320
#define OFF_XB    (OFF_WCAT + SZ_WCAT)
#define SZ_XB     ((unsigned long)T_*B_*XD_*2)    // 16,777,216
#define OFF_HBF16 (OFF_XB + SZ_XB)
#define SZ_HBF16  (2UL*B_*H_*2)                   // 262,144
#define OFF_PLAN  (OFF_HBF16 + SZ_HBF16)
#define SZ_PLAN   (4096UL)
#define OFF_CNT   (OFF_PLAN + SZ_PLAN)

__device__ __forceinline__ float sigm_(float x) { return 1.f / (1.f + __expf(-x)); }
__device__ __forceinline__ float tanh_(float x) { return 1.f - 2.f / (__expf(2.f * x) + 1.f); }
__device__ __forceinline__ short bf16_of(float f) {
    __hip_bfloat16 h = __float2bfloat16(f);
    return *reinterpret_cast<short*>(&h);
}
__device__ __forceinline__ float f_of_bf16(short s) {
    union { unsigned u; float f; } c;
    c.u = ((unsigned)(unsigned short)s) << 16;
    return c.f;
}

// ---- prep: concat W_ih|W_hh into bf16 Wcat[3072][1280] ----
__global__ void prep_wcat(const float* __restrict__ W_ih, const float* __restrict__ W_hh,
                          short* __restrict__ Wcat) {
    const int j = blockIdx.x;              // 0..3071
    for (int k = threadIdx.x; k < 1280; k += 256) {
        float v = (k < XD_) ? W_ih[j * XD_ + k] : W_hh[j * H_ + (k - XD_)];
        Wcat[(long)j * 1280 + k] = bf16_of(v);
    }
}

// ---- prep: transpose x [B][T][X] f32 -> xb [T][B][X] bf16 ----
__global__ void prep_xb(const float* __restrict__ x, short* __restrict__ xb) {
    const long total = (long)T_ * B_ * XD_;
    for (long i = (long)blockIdx.x * blockDim.x + threadIdx.x; i < total;
         i += (long)gridDim.x * blockDim.x) {
        int t   = (int)(i >> 14);
        int rem = (int)(i & 16383);
        int b   = rem >> 8;
        int k   = rem & 255;
        xb[i] = bf16_of(x[((long)(b * T_ + t)) * XD_ + k]);
    }
}

// ---- prep: packed per-step skip plan: bit0=alpha, bit1=beta, bits2+=lag ----
__global__ void prep_plan(const int* __restrict__ w1, const int* __restrict__ w2,
                          const int* __restrict__ ssp, int* __restrict__ plang) {
    int t = threadIdx.x;
    if (t > T_) return;
    if (t == T_) { plang[t] = (1 << 2); return; }
    int ss = ssp[0];
    int a = w1[t] & 1;
    int uz = 0, slot = 0;
    if (t < ss)            { if (2 * t < ss) uz = 1; else slot = ss - t - 1; }
    else if (t - ss < ss)  { uz = 1; }
    else                   { slot = 2 * ss - 1; }
    int bet = uz ? 0 : (w2[t] & 1);
    plang[t] = a | (bet << 1) | ((slot + 1) << 2);
}

// ---- prep: zero h16 slot0 + counters ----
__global__ void prep_zero(short* __restrict__ hbf16, unsigned* __restrict__ cnt) {
    int i = blockIdx.x * blockDim.x + threadIdx.x;
    if (i < B_ * H_) hbf16[i] = 0;
    if (i < 1024) cnt[i] = 0u;
}

// ---- persistent recurrent kernel: 256 WGs = 64 col-blocks x 4 batch-quarters ----
__global__ __launch_bounds__(256, 1) void persist_kernel(
    const short* __restrict__ Wcat, const short* __restrict__ xb,
    const float* __restrict__ b_ih, const float* __restrict__ b_hh,
    short* __restrict__ hbf16, const int* __restrict__ plang,
    unsigned* __restrict__ cnt, float* __restrict__ out) {

    __shared__ short Wlds[48 * 1280];        // 122,880 B  (XOR-swizzled rows)
    __shared__ float red[3][3][64][4];       // 9,216 B    cross-wave H partials
    __shared__ short ringl[16][16][20];      // 10,240 B   bf16 h history (skip path)
    __shared__ float hbls[2][16][20];        // 2,560 B    f32 blended-h (z path)
    __shared__ int   planl[T_ + 1];          // 2,052 B

    const int tid = threadIdx.x;
    const int w   = tid >> 6;
    const int l   = tid & 63;
    const int l15 = l & 15;
    const int lhi = l >> 4;
    const int wg  = blockIdx.x;
    const int c0  = (wg >> 2) << 4;     // 16 h-cols per WG
    const int m0  = (wg & 3) << 4;      // 16 batch rows per WG
    const int grp = wg & 7;
    const int jc0 = c0 + lhi * 4;       // this lane's 4 output cols

    // --- one-time: W slice -> LDS (swizzled: byte ^= (row&15)<<4), plan -> LDS ---
    for (int j = tid; j < 48 * 160; j += 256) {
        int r    = j / 160;
        int cbyt = (j - r * 160) * 16;
        int g    = r >> 4, i = r & 15;
        bf16x8 v = *(const bf16x8*)(Wcat + (long)(g * H_ + c0 + i) * 1280 + (cbyt >> 1));
        *(bf16x8*)((char*)Wlds + r * 2560 + (cbyt ^ (i << 4))) = v;
    }
    for (int j = tid; j <= T_; j += 256) planl[j] = plang[j];
    for (int j = tid; j < 2 * 16 * 20; j += 256) ((float*)hbls)[j] = 0.f;

    const f32x4 brc = *(const f32x4*)&b_ih[jc0]          + *(const f32x4*)&b_hh[jc0];
    const f32x4 bzc = *(const f32x4*)&b_ih[H_ + jc0]     + *(const f32x4*)&b_hh[H_ + jc0];
    const f32x4 bin = *(const f32x4*)&b_ih[2 * H_ + jc0];
    const f32x4 bhn = *(const f32x4*)&b_hh[2 * H_ + jc0];
    __syncthreads();

    const int swz = l15 << 4;
    auto arow = [&](int g, int kb) -> bf16x8 {
        return *(const bf16x8*)((const char*)Wlds + (g * 16 + l15) * 2560 + (kb ^ swz));
    };

    // wave0: x-projection pipeline register (computed one step ahead)
    f32x4 accX[3];
    auto xgemm = [&](int t) {
        accX[0] = accX[1] = accX[2] = (f32x4){0.f, 0.f, 0.f, 0.f};
        const short* xp = xb + ((long)t * B_ + m0 + l15) * XD_ + lhi * 8;
        #pragma unroll
        for (int it = 0; it < 8; ++it) {
            bf16x8 bfrag = *(const bf16x8*)(xp + it * 32);
            const int kb = (it * 32 + lhi * 8) * 2;
            accX[0] = __builtin_amdgcn_mfma_f32_16x16x32_bf16(arow(0, kb), bfrag, accX[0], 0, 0, 0);
            accX[1] = __builtin_amdgcn_mfma_f32_16x16x32_bf16(arow(1, kb), bfrag, accX[1], 0, 0, 0);
            accX[2] = __builtin_amdgcn_mfma_f32_16x16x32_bf16(arow(2, kb), bfrag, accX[2], 0, 0, 0);
        }
    };

    if (w == 0) xgemm(0);

    int cur = 0;
    for (int t = 0; t < T_; ++t) {
        // ---- waves 1-3: H-projection from h16[cur] via L2-bypassing loads ----
        if (w > 0) {
            f32x4 accH[3] = {{0.f,0.f,0.f,0.f},{0.f,0.f,0.f,0.f},{0.f,0.f,0.f,0.f}};
            const short* hb16 = hbf16 + (long)cur * (B_ * H_);
            auto hgemm = [&](auto ITC, int hk0) {
                constexpr int IT = decltype(ITC)::value;
                const short* sp = hb16 + (m0 + l15) * H_ + hk0 + lhi * 8;
                const u64*   hp = (const u64*)sp;
                u64 lo[IT], hi[IT];
                #pragma unroll
                for (int it = 0; it < IT; ++it) {
                    lo[it] = __hip_atomic_load(hp + it * 8,     __ATOMIC_RELAXED, __HIP_MEMORY_SCOPE_SYSTEM);
                    hi[it] = __hip_atomic_load(hp + it * 8 + 1, __ATOMIC_RELAXED, __HIP_MEMORY_SCOPE_SYSTEM);
                }
                #pragma unroll
                for (int it = 0; it < IT; ++it) {
                    union { u64 q[2]; bf16x8 v; } uu;
                    uu.q[0] = lo[it]; uu.q[1] = hi[it];
                    const int kb = (256 + hk0 + it * 32 + lhi * 8) * 2;
                    accH[0] = __builtin_amdgcn_mfma_f32_16x16x32_bf16(arow(0, kb), uu.v, accH[0], 0, 0, 0);
                    accH[1] = __builtin_amdgcn_mfma_f32_16x16x32_bf16(arow(1, kb), uu.v, accH[1], 0, 0, 0);
                    accH[2] = __builtin_amdgcn_mfma_f32_16x16x32_bf16(arow(2, kb), uu.v, accH[2], 0, 0, 0);
                }
            };
            if      (w == 1) hgemm(std::integral_constant<int, 11>{}, 0);
            else if (w == 2) hgemm(std::integral_constant<int, 11>{}, 352);
            else             hgemm(std::integral_constant<int, 10>{}, 704);
            #pragma unroll
            for (int g = 0; g < 3; ++g)
                *(f32x4*)&red[g][w - 1][l][0] = accH[g];
        }
        __syncthreads();   // (A) partials ready

        if (w == 0) {
            f32x4 Hr = {0.f,0.f,0.f,0.f}, Hz = {0.f,0.f,0.f,0.f}, Hn = {0.f,0.f,0.f,0.f};
            #pragma unroll
            for (int s = 0; s < 3; ++s) {
                Hr += *(const f32x4*)&red[0][s][l][0];
                Hz += *(const f32x4*)&red[1][s][l][0];
                Hn += *(const f32x4*)&red[2][s][l][0];
            }
            const int   p   = planl[t + 1];
            const float al  = (float)(p & 1);
            const float bet = (float)((p >> 1) & 1);
            const int   lg  = p >> 2;

            const f32x4 hb = *(const f32x4*)&hbls[cur][l15][lhi * 4];
            f32x4 hn;
            #pragma unroll
            for (int r = 0; r < 4; ++r) {
                float rg = sigm_(accX[0][r] + Hr[r] + brc[r]);
                float zg = sigm_(accX[1][r] + Hz[r] + bzc[r]);
                float ng = tanh_(accX[2][r] + bin[r] + rg * (Hn[r] + bhn[r]));
                hn[r] = (1.f - zg) * ng + zg * hb[r];
            }
            // ring write (bf16), skip read, blend
            union { short s[4]; u64 q; } pk;
            #pragma unroll
            for (int r = 0; r < 4; ++r) pk.s[r] = bf16_of(hn[r]);
            *(bf16x4*)&ringl[t & 15][l15][lhi * 4] = *(bf16x4*)pk.s;
            const bf16x4 old4 = *(const bf16x4*)&ringl[(t + 1 - lg) & 15][l15][lhi * 4];
            f32x4 hbn;
            #pragma unroll
            for (int r = 0; r < 4; ++r)
                hbn[r] = al * hn[r] + bet * f_of_bf16(old4[r]);
            *(f32x4*)&hbls[cur ^ 1][l15][lhi * 4] = hbn;
            // publish next-step h16 (bypass L2 -> coherent at MALL)
            #pragma unroll
            for (int r = 0; r < 4; ++r) pk.s[r] = bf16_of(hbn[r]);
            u64* pub = (u64*)(hbf16 + (long)(cur ^ 1) * (B_ * H_) + (m0 + l15) * H_ + jc0);
            __hip_atomic_store(pub, pk.q, __ATOMIC_RELAXED, __HIP_MEMORY_SCOPE_SYSTEM);

            if (t == T_ - 1) {
                f32x4 o = hn; o[0] *= 2.f; o[1] *= 2.f; o[2] *= 2.f; o[3] *= 2.f;
                *(f32x4*)&out[(long)(m0 + l15) * H_ + jc0] = o;
            }

            if (t + 1 < T_) {
                if (tid == 0) {
                    asm volatile("s_waitcnt vmcnt(0)" ::: "memory");
                    unsigned old = __hip_atomic_fetch_add(&cnt[grp * 32], 1u,
                                        __ATOMIC_RELAXED, __HIP_MEMORY_SCOPE_AGENT);
                    if (old == 32u * (unsigned)(t + 1) - 1u)
                        __hip_atomic_fetch_add(&cnt[512], 1u,
                                        __ATOMIC_RELAXED, __HIP_MEMORY_SCOPE_AGENT);
                }
                xgemm(t + 1);   // hide arrival latency with next step's x-GEMM
                if (tid == 0) {
                    const unsigned tgt = 8u * (unsigned)(t + 1);
                    while (__hip_atomic_load(&cnt[512], __ATOMIC_RELAXED,
                                             __HIP_MEMORY_SCOPE_AGENT) < tgt)
                        __builtin_amdgcn_s_sleep(2);
                }
            }
        }
        __syncthreads();   // (B) barrier passed; h16[cur^1] globally ready
        cur ^= 1;
    }
}

extern "C" void kernel_launch(void* const* d_in, const int* in_sizes, int n_in,
                              void* d_out, int out_size, void* d_ws, size_t ws_size,
                              hipStream_t stream) {
    const float* x    = (const float*)d_in[0];
    const float* W_ih = (const float*)d_in[1];
    const float* W_hh = (const float*)d_in[2];
    const float* b_ih = (const float*)d_in[3];
    const float* b_hh = (const float*)d_in[4];
    const int*   w1   = (const int*)d_in[5];
    const int*   w2   = (const int*)d_in[6];
    const int*   ssp  = (const int*)d_in[7];
    float* out = (float*)d_out;

    char* ws = (char*)d_ws;
    short*    Wcat  = (short*)(ws + OFF_WCAT);
    short*    xbuf  = (short*)(ws + OFF_XB);
    short*    hbf16 = (short*)(ws + OFF_HBF16);
    int*      plang = (int*)(ws + OFF_PLAN);
    unsigned* cnt   = (unsigned*)(ws + OFF_CNT);

    prep_wcat<<<3072, 256, 0, stream>>>(W_ih, W_hh, Wcat);
    prep_xb<<<8192, 256, 0, stream>>>(x, xbuf);
    prep_plan<<<1, 1024, 0, stream>>>(w1, w2, ssp, plang);
    prep_zero<<<256, 256, 0, stream>>>(hbf16, cnt);

    persist_kernel<<<NWG, 256, 0, stream>>>(Wcat, xbuf, b_ih, b_hh,
                                            hbf16, plang, cnt, out);
}